// Round 13
// baseline (3432.857 us; speedup 1.0000x reference)
//
#include <hip/hip_runtime.h>
#include <stdint.h>

#define Bsz 4096
#define Tsz 24
#define Isz 128
#define Hsz 512
#define Wsz 32
#define Msz (Bsz * Tsz)   // 98304 flat rows (b*T+t)

typedef __attribute__((ext_vector_type(8))) short short8;
typedef __attribute__((ext_vector_type(4))) float f32x4;
typedef unsigned short u16;

__device__ __forceinline__ float bf2f(u16 u) {
    union { unsigned int i; float f; } v; v.i = ((unsigned int)u) << 16; return v.f;
}
__device__ __forceinline__ u16 f2bf(float f) {
    union { float f; unsigned int i; } v; v.f = f;
    unsigned int r = v.i + 0x7fffu + ((v.i >> 16) & 1u);
    return (u16)(r >> 16);
}
__device__ __forceinline__ float sigm(float x) { return 1.0f / (1.0f + expf(-x)); }

__device__ __forceinline__ f32x4 MF(short8 a, short8 b, f32x4 c) {
    return __builtin_amdgcn_mfma_f32_16x16x32_bf16(a, b, c, 0, 0, 0);
}
__device__ __forceinline__ short8 ntload8(const u16* p) {
    return __builtin_nontemporal_load((const short8*)p);
}

#define GLOAD_LDS16(SRC, DST) \
    __builtin_amdgcn_global_load_lds( \
        (__attribute__((address_space(1))) void*)(SRC), \
        (__attribute__((address_space(3))) void*)(DST), 16, 0, 0)

// ---------------- f32 -> bf16 conversion ----------------------------------
__global__ __launch_bounds__(256) void convert_big(
    const float* __restrict__ src, u16* __restrict__ dst, int n)
{
    int i = (blockIdx.x * 256 + threadIdx.x) * 4;
    if (i + 4 <= n) {
        float4 v = *(const float4*)(src + i);
        dst[i + 0] = f2bf(v.x); dst[i + 1] = f2bf(v.y);
        dst[i + 2] = f2bf(v.z); dst[i + 3] = f2bf(v.w);
    }
}

struct ConvDesc { const float* src; u16* dst; int n; };
struct ConvTab { ConvDesc d[13]; };

__global__ __launch_bounds__(256) void convert_many(ConvTab tab)
{
    ConvDesc cd = tab.d[blockIdx.y];
    for (int i = (blockIdx.x * 256 + threadIdx.x) * 4; i < cd.n;
         i += gridDim.x * 256 * 4) {
        float4 v = *(const float4*)(cd.src + i);
        cd.dst[i + 0] = f2bf(v.x); cd.dst[i + 1] = f2bf(v.y);
        cd.dst[i + 2] = f2bf(v.z); cd.dst[i + 3] = f2bf(v.w);
    }
}

// ======================= prepass GEMM machinery (r5-exact) =================
struct Seg { const u16* A; int astr; int shift; const u16* W; int wstr; int nkb; };

__device__ __forceinline__ void stage_half(
    u16* ldsT, const u16* gbase, int rstr, int rvf,
    const u16* zerobuf, int wid, int lane)
{
#pragma unroll
    for (int q = 0; q < 4; ++q) {
        int c   = wid * 4 + q;
        int lin = c * 64 + lane;
        int row = lin >> 3;
        int gc  = lin & 7;
        const u16* src = (row >= rvf)
            ? (gbase + (long)row * rstr + ((gc ^ (row & 7)) << 3))
            : zerobuf;
        GLOAD_LDS16(src, ldsT + c * 512);
    }
}

__device__ __forceinline__ void stage_step(
    const Seg* segs, int nseg, int kb, u16* ldsA, u16* ldsB,
    int m0, int n0, const u16* zerobuf, int wid, int lane)
{
    Seg s = segs[0];
    int kloc = kb;
    if (nseg > 1 && kloc >= s.nkb) {
        kloc -= s.nkb; s = segs[1];
        if (nseg > 2 && kloc >= s.nkb) { kloc -= s.nkb; s = segs[2]; }
    }
    int base_row = m0 + s.shift;
    int rvf = base_row < 0 ? -base_row : 0;
    stage_half(ldsA, s.A + (long)base_row * s.astr + kloc * 64, s.astr, rvf,
               zerobuf, wid, lane);
    stage_half(ldsB, s.W + (long)n0 * s.wstr + kloc * 64, s.wstr, 0,
               zerobuf, wid, lane);
}

__device__ __forceinline__ void compute_tile(
    f32x4 acc[4][4], const u16* Ab, const u16* Bb, int wr, int wc, int lane)
{
    const int l15 = lane & 15;
    const int hi = lane >> 4;
#pragma unroll
    for (int ks = 0; ks < 2; ++ks) {
        int kg = ks * 4 + hi;
        short8 a[4], b[4];
#pragma unroll
        for (int am = 0; am < 4; ++am) {
            int row = wr * 64 + am * 16 + l15;
            a[am] = *(const short8*)(Ab + row * 64 + ((kg ^ (row & 7)) << 3));
        }
#pragma unroll
        for (int bn = 0; bn < 4; ++bn) {
            int row = wc * 64 + bn * 16 + l15;
            b[bn] = *(const short8*)(Bb + row * 64 + ((kg ^ (row & 7)) << 3));
        }
#pragma unroll
        for (int am = 0; am < 4; ++am)
#pragma unroll
            for (int bn = 0; bn < 4; ++bn)
                acc[am][bn] = MF(a[am], b[bn], acc[am][bn]);
    }
}

#define GEMM_CORE(SEGS, NSEG, M0, N0W)                                          \
    __shared__ u16 lds[2][2][128 * 64];                                         \
    const int lane = threadIdx.x & 63;                                          \
    const int wid  = threadIdx.x >> 6;                                          \
    const int wr = wid >> 1, wc = wid & 1;                                      \
    f32x4 acc[4][4];                                                            \
    _Pragma("unroll") for (int i_ = 0; i_ < 4; ++i_)                            \
    _Pragma("unroll") for (int j_ = 0; j_ < 4; ++j_)                            \
        acc[i_][j_] = f32x4{0, 0, 0, 0};                                        \
    int nkb = 0;                                                                \
    for (int s_ = 0; s_ < (NSEG); ++s_) nkb += (SEGS)[s_].nkb;                  \
    stage_step((SEGS), (NSEG), 0, lds[0][0], lds[0][1], (M0), (N0W),            \
               zerobuf, wid, lane);                                             \
    int cur = 0;                                                                \
    for (int kb = 0; kb < nkb; ++kb) {                                          \
        __syncthreads();                                                        \
        if (kb + 1 < nkb)                                                       \
            stage_step((SEGS), (NSEG), kb + 1, lds[cur ^ 1][0],                 \
                       lds[cur ^ 1][1], (M0), (N0W), zerobuf, wid, lane);       \
        compute_tile(acc, lds[cur][0], lds[cur][1], wr, wc, lane);              \
        cur ^= 1;                                                               \
    }

// ---------------- e = sigmoid(xw @ w_e^T + b_e), e layout [b*T+t][512] -----
__global__ __launch_bounds__(256) void ekernel(
    const u16* __restrict__ xw, const u16* __restrict__ w_e,
    const float* __restrict__ b_e, u16* __restrict__ eout)
{
    const int lane = threadIdx.x & 63;
    const int wid  = threadIdx.x >> 6;
    const int m0 = blockIdx.x * 64 + (wid >> 1) * 32;
    const int n0 = blockIdx.y * 64 + (wid & 1) * 32;
    f32x4 acc[2][2];
    acc[0][0] = f32x4{0,0,0,0}; acc[0][1] = f32x4{0,0,0,0};
    acc[1][0] = f32x4{0,0,0,0}; acc[1][1] = f32x4{0,0,0,0};
    const int l15 = lane & 15;
    const int klane = (lane >> 4) * 8;
    short8 b0 = *(const short8*)(w_e + (n0 + l15) * Wsz + klane);
    short8 b1 = *(const short8*)(w_e + (n0 + 16 + l15) * Wsz + klane);
#pragma unroll
    for (int am = 0; am < 2; ++am) {
        short8 a = *(const short8*)(xw + (long)(m0 + am * 16 + l15) * Wsz + klane);
        acc[am][0] = MF(a, b0, acc[am][0]);
        acc[am][1] = MF(a, b1, acc[am][1]);
    }
    const int col = lane & 15;
    const int r0 = (lane >> 4) * 4;
#pragma unroll
    for (int am = 0; am < 2; ++am)
#pragma unroll
        for (int bn = 0; bn < 2; ++bn)
#pragma unroll
            for (int i = 0; i < 4; ++i) {
                long row = m0 + am * 16 + r0 + i;
                int g = n0 + bn * 16 + col;
                eout[row * Hsz + g] = f2bf(sigm(acc[am][bn][i] + b_e[g]));
            }
}

// ---------------- pre-pass: writes frag-permuted prep (r9-exact) -----------
__global__ __launch_bounds__(256, 2) void prepass_kernel(
    const u16* __restrict__ x, const u16* __restrict__ e,
    const u16* __restrict__ w_d, const u16* __restrict__ w_w,
    const u16* __restrict__ w_m, const u16* __restrict__ w_rx,
    const u16* __restrict__ w_re, const u16* __restrict__ w_zx,
    const u16* __restrict__ w_ze, const u16* __restrict__ w_hx,
    const float* __restrict__ b_r, const float* __restrict__ b_z,
    const float* __restrict__ b_h,
    const u16* __restrict__ zerobuf, u16* __restrict__ prep)
{
    const int m0 = blockIdx.x * 128;
    const int y = blockIdx.y;
    const int group = y >> 2;
    const int nin = (y & 3) * 128;
    Seg segs[3];
    int nseg;
    const float* bias = nullptr;
    if (group == 0) {
        segs[0] = { x, Isz, -1 * Tsz,  w_d, Isz, Isz / 64 };
        segs[1] = { x, Isz, -7 * Tsz,  w_w, Isz, Isz / 64 };
        segs[2] = { x, Isz, -30 * Tsz, w_m, Isz, Isz / 64 };
        nseg = 3;
    } else if (group == 1) {
        segs[0] = { x, Isz, 0, w_rx, Isz, Isz / 64 };
        segs[1] = { e, Hsz, 0, w_re, Hsz, Hsz / 64 };
        nseg = 2; bias = b_r;
    } else if (group == 2) {
        segs[0] = { x, Isz, 0, w_zx, Isz, Isz / 64 };
        segs[1] = { e, Hsz, 0, w_ze, Hsz, Hsz / 64 };
        nseg = 2; bias = b_z;
    } else {
        segs[0] = { x, Isz, 0, w_hx, Isz, Isz / 64 };
        nseg = 1; bias = b_h;
    }
    GEMM_CORE(segs, nseg, m0, nin)
    const int l15 = lane & 15, hi4v = (lane >> 4) * 4;
#pragma unroll
    for (int am = 0; am < 4; ++am)
#pragma unroll
        for (int bn = 0; bn < 4; ++bn) {
            int colH = nin + wc * 64 + bn * 16 + l15;
            float bv = bias ? bias[colH] : 0.0f;
            int wv = colH >> 5, ntv = (colH >> 4) & 1, l15v = colH & 15;
#pragma unroll
            for (int i = 0; i < 4; ++i) {
                long m = m0 + wr * 64 + am * 16 + hi4v + i;
                int b = (int)(m / Tsz), t = (int)(m % Tsz);
                int bblk = b >> 4, rowin = b & 15;
                int hiv = rowin >> 2, iv = rowin & 3;
                long idx = (((long)(bblk * Tsz + t) * 4 + group) * 16 + wv) * 512
                           + (hiv * 16 + l15v) * 8 + ntv * 4 + iv;
                prep[idx] = f2bf(acc[am][bn][i] + bv);
            }
        }
}

// ======================= persistent recurrence =============================
// 256 blocks x 1024 thr (16 waves). Block owns 16 batch rows. Wave owns 32
// output cols. Weights staged global->LDS in 32KB chunks, TRIPLE-buffered
// with counted vmcnt(2) + raw s_barrier (chunk c+2 staged after barrier c;
// loads span 2 periods). Weight buf layout beat-conflict-free:
// granule (col,sub) at slot (col>>1)*8 + ((sub+4*(col&1)) ^ ((col>>1)&7)).
// State LDS row stride 528 u16 (conflict-free per-beat, r11-verified).
#define SROW 528

__device__ __forceinline__ int swz(int row, int col) {
    return row * SROW + ((((col >> 3) ^ (row & 7)) << 3) | (col & 7));
}

// stage chunk c of Wm (512 cols x 32 k) into 32KB buf; wave covers slots
// [wave*128, wave*128+128). Source pre-swizzled so linear LDS dest lands
// each granule at its swizzled slot (rule #21).
__device__ __forceinline__ void stage_chunk(
    const u16* __restrict__ Wm, int c, u16* buf, int wave, int lane)
{
    int s1 = wave * 128 + lane;
    int s2 = s1 + 64;
    int p1 = s1 >> 3, g1 = (s1 & 7) ^ (p1 & 7);
    int p2 = s2 >> 3, g2 = (s2 & 7) ^ (p2 & 7);
    GLOAD_LDS16(Wm + (long)(2 * p1 + (g1 >> 2)) * 512 + c * 32 + (g1 & 3) * 8,
                buf + wave * 1024);
    GLOAD_LDS16(Wm + (long)(2 * p2 + (g2 >> 2)) * 512 + c * 32 + (g2 & 3) * 8,
                buf + wave * 1024 + 512);
}

// one pipelined chunk-iteration: wait own chunk C resident, barrier, stage
// chunk C+2 (after barrier => no wave still reads that buffer), compute C.
#define WITER(C, RB, SB, VM) { \
    asm volatile("s_waitcnt vmcnt(" VM ")" ::: "memory"); \
    asm volatile("s_barrier" ::: "memory"); \
    if ((C) < 14) stage_chunk(Wm, (C) + 2, SB, wave, lane); \
    short8 b0 = *(const short8*)((RB) + bo0); \
    short8 b1 = *(const short8*)((RB) + bo0 + 512); \
    short8 a = *(const short8*)(ap + ((((C) * 4 + hi) ^ rx) << 3)); \
    acc[0] = MF(a, b0, acc[0]); \
    acc[1] = MF(a, b1, acc[1]); }

__device__ __forceinline__ void wpass_staged(
    f32x4 acc[2], const u16* aS, const u16* __restrict__ Wm,
    u16* wb0, u16* wb1, u16* wb2,
    int bo0, int rx, int hi, int wave, int lane, int l15)
{
    const u16* ap = aS + l15 * SROW;
    stage_chunk(Wm, 0, wb0, wave, lane);
    stage_chunk(Wm, 1, wb1, wave, lane);
    WITER(0,  wb0, wb2, "2")
    WITER(1,  wb1, wb0, "2")
    WITER(2,  wb2, wb1, "2")
    WITER(3,  wb0, wb2, "2")
    WITER(4,  wb1, wb0, "2")
    WITER(5,  wb2, wb1, "2")
    WITER(6,  wb0, wb2, "2")
    WITER(7,  wb1, wb0, "2")
    WITER(8,  wb2, wb1, "2")
    WITER(9,  wb0, wb2, "2")
    WITER(10, wb1, wb0, "2")
    WITER(11, wb2, wb1, "2")
    WITER(12, wb0, wb2, "2")
    WITER(13, wb1, wb0, "2")
    WITER(14, wb2, wb1, "2")
    WITER(15, wb0, wb2, "0")
}

#define FOR_FRAG \
    _Pragma("unroll") for (int nt2 = 0; nt2 < 2; ++nt2) \
    _Pragma("unroll") for (int i = 0; i < 4; ++i)

__global__ __launch_bounds__(1024, 4) void rnn_kernel(
    const u16* __restrict__ prep, const u16* __restrict__ w_t_,
    const u16* __restrict__ w_rh, const u16* __restrict__ w_zh,
    const u16* __restrict__ w_hh, float* __restrict__ out)
{
    __shared__ __align__(16) u16 hS[16 * SROW];
    __shared__ __align__(16) u16 hoS[16 * SROW];
    __shared__ __align__(16) u16 rhS[16 * SROW];
    __shared__ __align__(16) u16 wbuf0[16 * 1024];
    __shared__ __align__(16) u16 wbuf1[16 * 1024];
    __shared__ __align__(16) u16 wbuf2[16 * 1024];
    const int tid = threadIdx.x;
    const int lane = tid & 63;
    const int wave = tid >> 6;
    const int l15 = lane & 15, hi = lane >> 4;
    const int rx = l15 & 7;
    const int n0 = wave * 32;
    const long b0 = (long)blockIdx.x * 16;
    // weight-buffer read offset (u16): slot*8, slot = wave*16+(l15>>1) row of
    // 8, XOR key = l15>>1; second col (+16) is slot+64 -> +512 u16.
    const int bo0 = (wave * 128 + (l15 >> 1) * 8
                     + ((hi + 4 * (l15 & 1)) ^ (l15 >> 1))) * 8;

    for (int i = tid * 8; i < 16 * SROW; i += 1024 * 8)
        *(short8*)(hS + i) = (short8)0;
    __syncthreads();

    const u16* pbase = prep + (long)blockIdx.x * (Tsz * 4 * 8192)
                       + wave * 512 + lane * 8;

#pragma unroll 1
    for (int t = 0; t < Tsz; ++t) {
        const u16* pt = pbase + (long)t * 4 * 8192;
        short8 po = ntload8(pt);
        short8 pr = ntload8(pt + 8192);
        short8 pz = ntload8(pt + 2 * 8192);
        short8 ph = ntload8(pt + 3 * 8192);

        // ---- stage A: ho = sigm(pre_o + h @ w_t^T) ----
        f32x4 accO[2];
        accO[0] = f32x4{0,0,0,0}; accO[1] = f32x4{0,0,0,0};
        wpass_staged(accO, hS, w_t_, wbuf0, wbuf1, wbuf2,
                     bo0, rx, hi, wave, lane, l15);
        float hov[2][4];
        FOR_FRAG {
            float v = sigm(accO[nt2][i] + bf2f((u16)po[nt2 * 4 + i]));
            hov[nt2][i] = v;
            hoS[swz(hi * 4 + i, n0 + nt2 * 16 + l15)] = f2bf(v);
        }
        __syncthreads();   // hoS ready; wbuf reads of pass A done

        // ---- stage B: r = sigm(pre_r + ho @ w_rh^T) ----
        f32x4 accR[2];
        accR[0] = f32x4{0,0,0,0}; accR[1] = f32x4{0,0,0,0};
        wpass_staged(accR, hoS, w_rh, wbuf0, wbuf1, wbuf2,
                     bo0, rx, hi, wave, lane, l15);
        __syncthreads();   // wbuf reads done before Z restages

        //      z = sigm(pre_z + ho @ w_zh^T); rh = r*ho -> rhS
        f32x4 accZ[2];
        accZ[0] = f32x4{0,0,0,0}; accZ[1] = f32x4{0,0,0,0};
        wpass_staged(accZ, hoS, w_zh, wbuf0, wbuf1, wbuf2,
                     bo0, rx, hi, wave, lane, l15);
        float zv[2][4];
        FOR_FRAG {
            zv[nt2][i] = sigm(accZ[nt2][i] + bf2f((u16)pz[nt2 * 4 + i]));
            float rv = sigm(accR[nt2][i] + bf2f((u16)pr[nt2 * 4 + i]));
            rhS[swz(hi * 4 + i, n0 + nt2 * 16 + l15)] = f2bf(rv * hov[nt2][i]);
        }
        __syncthreads();   // rhS ready

        // ---- stage C: h~ = tanh(pre_h + rh @ w_hh^T); h = (1-z)ho + z h~ ----
        f32x4 accH[2];
        accH[0] = f32x4{0,0,0,0}; accH[1] = f32x4{0,0,0,0};
        wpass_staged(accH, rhS, w_hh, wbuf0, wbuf1, wbuf2,
                     bo0, rx, hi, wave, lane, l15);
        FOR_FRAG {
            int row = hi * 4 + i, col = n0 + nt2 * 16 + l15;
            float htl = tanhf(accH[nt2][i] + bf2f((u16)ph[nt2 * 4 + i]));
            float z = zv[nt2][i];
            float hn = (1.0f - z) * hov[nt2][i] + z * htl;
            __builtin_nontemporal_store(
                hn, &out[((b0 + row) * Tsz + t) * (long)Hsz + col]);
            hS[swz(row, col)] = f2bf(hn);
        }
        __syncthreads();   // hS ready for next step
    }
}

extern "C" void kernel_launch(void* const* d_in, const int* in_sizes, int n_in,
                              void* d_out, int out_size, void* d_ws, size_t ws_size,
                              hipStream_t stream) {
    const float* x_f    = (const float*)d_in[0];
    const float* xw_f   = (const float*)d_in[1];
    const float* w_rx_f = (const float*)d_in[2];
    const float* w_rh_f = (const float*)d_in[3];
    const float* w_re_f = (const float*)d_in[4];
    const float* b_r    = (const float*)d_in[5];
    const float* w_zx_f = (const float*)d_in[6];
    const float* w_zh_f = (const float*)d_in[7];
    const float* w_ze_f = (const float*)d_in[8];
    const float* b_z    = (const float*)d_in[9];
    const float* w_hx_f = (const float*)d_in[10];
    const float* w_hh_f = (const float*)d_in[11];
    const float* b_h    = (const float*)d_in[12];
    const float* w_d_f  = (const float*)d_in[13];
    const float* w_w_f  = (const float*)d_in[14];
    const float* w_m_f  = (const float*)d_in[15];
    const float* w_t_f  = (const float*)d_in[16];
    const float* w_e_f  = (const float*)d_in[17];
    const float* b_e    = (const float*)d_in[18];
    float* out = (float*)d_out;

    char* ws = (char*)d_ws;
    size_t off = 0;
    auto alloc = [&](size_t bytes) {
        size_t o = off; off = (off + bytes + 255) & ~(size_t)255; return o;
    };
    const size_t nx  = (size_t)Msz * Isz;
    const size_t nxw = (size_t)Msz * Wsz;

    u16* x_bf  = (u16*)(ws + alloc(nx * 2));
    u16* xw_bf = (u16*)(ws + alloc(nxw * 2));
    u16* w_rx  = (u16*)(ws + alloc(Hsz * Isz * 2));
    u16* w_rh  = (u16*)(ws + alloc(Hsz * Hsz * 2));
    u16* w_re  = (u16*)(ws + alloc(Hsz * Hsz * 2));
    u16* w_zx  = (u16*)(ws + alloc(Hsz * Isz * 2));
    u16* w_zh  = (u16*)(ws + alloc(Hsz * Hsz * 2));
    u16* w_ze  = (u16*)(ws + alloc(Hsz * Hsz * 2));
    u16* w_hx  = (u16*)(ws + alloc(Hsz * Isz * 2));
    u16* w_hh  = (u16*)(ws + alloc(Hsz * Hsz * 2));
    u16* w_d   = (u16*)(ws + alloc(Hsz * Isz * 2));
    u16* w_w   = (u16*)(ws + alloc(Hsz * Isz * 2));
    u16* w_m   = (u16*)(ws + alloc(Hsz * Isz * 2));
    u16* w_t   = (u16*)(ws + alloc(Hsz * Hsz * 2));
    u16* w_e   = (u16*)(ws + alloc(Hsz * Wsz * 2));
    u16* e_bf  = (u16*)(ws + alloc((size_t)Msz * Hsz * 2));   // 96 MB [b*T+t]
    u16* prep  = (u16*)(ws + alloc((size_t)Msz * 2048 * 2));  // 384 MB permuted
    u16* zerobuf = (u16*)(ws + alloc(256));

    convert_big<<<(int)(nx / 1024), 256, 0, stream>>>(x_f, x_bf, (int)nx);
    convert_big<<<(int)(nxw / 1024), 256, 0, stream>>>(xw_f, xw_bf, (int)nxw);
    ConvTab tab;
    tab.d[0]  = { w_rx_f, w_rx, Hsz * Isz };
    tab.d[1]  = { w_rh_f, w_rh, Hsz * Hsz };
    tab.d[2]  = { w_re_f, w_re, Hsz * Hsz };
    tab.d[3]  = { w_zx_f, w_zx, Hsz * Isz };
    tab.d[4]  = { w_zh_f, w_zh, Hsz * Hsz };
    tab.d[5]  = { w_ze_f, w_ze, Hsz * Hsz };
    tab.d[6]  = { w_hx_f, w_hx, Hsz * Isz };
    tab.d[7]  = { w_hh_f, w_hh, Hsz * Hsz };
    tab.d[8]  = { w_d_f,  w_d,  Hsz * Isz };
    tab.d[9]  = { w_w_f,  w_w,  Hsz * Isz };
    tab.d[10] = { w_m_f,  w_m,  Hsz * Isz };
    tab.d[11] = { w_t_f,  w_t,  Hsz * Hsz };
    tab.d[12] = { w_e_f,  w_e,  Hsz * Wsz };
    convert_many<<<dim3(256, 13), 256, 0, stream>>>(tab);
    hipMemsetAsync(zerobuf, 0, 256, stream);

    // e = sigmoid(xw @ w_e^T + b_e)  [98304 x 512], layout [b*T+t]
    ekernel<<<dim3(Msz / 64, Hsz / 64), 256, 0, stream>>>(xw_bf, w_e, b_e, e_bf);

    // pre-pass: all input-only projections, frag-permuted output
    prepass_kernel<<<dim3(Msz / 128, 16), 256, 0, stream>>>(
        x_bf, e_bf, w_d, w_w, w_m, w_rx, w_re, w_zx, w_ze, w_hx,
        b_r, b_z, b_h, zerobuf, prep);

    // persistent recurrence: 256 blocks x 16 waves, pipelined staged weights
    rnn_kernel<<<Bsz / 16, 1024, 0, stream>>>(prep, w_t, w_rh, w_zh, w_hh, out);
}

// Round 14
// 1733.177 us; speedup vs baseline: 1.9807x; 1.9807x over previous
//
#include <hip/hip_runtime.h>
#include <stdint.h>

#define Bsz 4096
#define Tsz 24
#define Isz 128
#define Hsz 512
#define Wsz 32
#define Msz (Bsz * Tsz)   // 98304 flat rows (b*T+t)

typedef __attribute__((ext_vector_type(8))) short short8;
typedef __attribute__((ext_vector_type(4))) float f32x4;
typedef unsigned short u16;

__device__ __forceinline__ float bf2f(u16 u) {
    union { unsigned int i; float f; } v; v.i = ((unsigned int)u) << 16; return v.f;
}
__device__ __forceinline__ u16 f2bf(float f) {
    union { float f; unsigned int i; } v; v.f = f;
    unsigned int r = v.i + 0x7fffu + ((v.i >> 16) & 1u);
    return (u16)(r >> 16);
}
__device__ __forceinline__ float sigm(float x) { return 1.0f / (1.0f + expf(-x)); }

__device__ __forceinline__ f32x4 MF(short8 a, short8 b, f32x4 c) {
    return __builtin_amdgcn_mfma_f32_16x16x32_bf16(a, b, c, 0, 0, 0);
}
__device__ __forceinline__ short8 ntload8(const u16* p) {
    return __builtin_nontemporal_load((const short8*)p);
}

#define GLOAD_LDS16(SRC, DST) \
    __builtin_amdgcn_global_load_lds( \
        (__attribute__((address_space(1))) void*)(SRC), \
        (__attribute__((address_space(3))) void*)(DST), 16, 0, 0)

// ---------------- f32 -> bf16 conversion ----------------------------------
__global__ __launch_bounds__(256) void convert_big(
    const float* __restrict__ src, u16* __restrict__ dst, int n)
{
    int i = (blockIdx.x * 256 + threadIdx.x) * 4;
    if (i + 4 <= n) {
        float4 v = *(const float4*)(src + i);
        dst[i + 0] = f2bf(v.x); dst[i + 1] = f2bf(v.y);
        dst[i + 2] = f2bf(v.z); dst[i + 3] = f2bf(v.w);
    }
}

struct ConvDesc { const float* src; u16* dst; int n; };
struct ConvTab { ConvDesc d[13]; };

__global__ __launch_bounds__(256) void convert_many(ConvTab tab)
{
    ConvDesc cd = tab.d[blockIdx.y];
    for (int i = (blockIdx.x * 256 + threadIdx.x) * 4; i < cd.n;
         i += gridDim.x * 256 * 4) {
        float4 v = *(const float4*)(cd.src + i);
        cd.dst[i + 0] = f2bf(v.x); cd.dst[i + 1] = f2bf(v.y);
        cd.dst[i + 2] = f2bf(v.z); cd.dst[i + 3] = f2bf(v.w);
    }
}

// ======================= prepass GEMM machinery (r5-exact) =================
struct Seg { const u16* A; int astr; int shift; const u16* W; int wstr; int nkb; };

__device__ __forceinline__ void stage_half(
    u16* ldsT, const u16* gbase, int rstr, int rvf,
    const u16* zerobuf, int wid, int lane)
{
#pragma unroll
    for (int q = 0; q < 4; ++q) {
        int c   = wid * 4 + q;
        int lin = c * 64 + lane;
        int row = lin >> 3;
        int gc  = lin & 7;
        const u16* src = (row >= rvf)
            ? (gbase + (long)row * rstr + ((gc ^ (row & 7)) << 3))
            : zerobuf;
        GLOAD_LDS16(src, ldsT + c * 512);
    }
}

__device__ __forceinline__ void stage_step(
    const Seg* segs, int nseg, int kb, u16* ldsA, u16* ldsB,
    int m0, int n0, const u16* zerobuf, int wid, int lane)
{
    Seg s = segs[0];
    int kloc = kb;
    if (nseg > 1 && kloc >= s.nkb) {
        kloc -= s.nkb; s = segs[1];
        if (nseg > 2 && kloc >= s.nkb) { kloc -= s.nkb; s = segs[2]; }
    }
    int base_row = m0 + s.shift;
    int rvf = base_row < 0 ? -base_row : 0;
    stage_half(ldsA, s.A + (long)base_row * s.astr + kloc * 64, s.astr, rvf,
               zerobuf, wid, lane);
    stage_half(ldsB, s.W + (long)n0 * s.wstr + kloc * 64, s.wstr, 0,
               zerobuf, wid, lane);
}

__device__ __forceinline__ void compute_tile(
    f32x4 acc[4][4], const u16* Ab, const u16* Bb, int wr, int wc, int lane)
{
    const int l15 = lane & 15;
    const int hi = lane >> 4;
#pragma unroll
    for (int ks = 0; ks < 2; ++ks) {
        int kg = ks * 4 + hi;
        short8 a[4], b[4];
#pragma unroll
        for (int am = 0; am < 4; ++am) {
            int row = wr * 64 + am * 16 + l15;
            a[am] = *(const short8*)(Ab + row * 64 + ((kg ^ (row & 7)) << 3));
        }
#pragma unroll
        for (int bn = 0; bn < 4; ++bn) {
            int row = wc * 64 + bn * 16 + l15;
            b[bn] = *(const short8*)(Bb + row * 64 + ((kg ^ (row & 7)) << 3));
        }
#pragma unroll
        for (int am = 0; am < 4; ++am)
#pragma unroll
            for (int bn = 0; bn < 4; ++bn)
                acc[am][bn] = MF(a[am], b[bn], acc[am][bn]);
    }
}

#define GEMM_CORE(SEGS, NSEG, M0, N0W)                                          \
    __shared__ u16 lds[2][2][128 * 64];                                         \
    const int lane = threadIdx.x & 63;                                          \
    const int wid  = threadIdx.x >> 6;                                          \
    const int wr = wid >> 1, wc = wid & 1;                                      \
    f32x4 acc[4][4];                                                            \
    _Pragma("unroll") for (int i_ = 0; i_ < 4; ++i_)                            \
    _Pragma("unroll") for (int j_ = 0; j_ < 4; ++j_)                            \
        acc[i_][j_] = f32x4{0, 0, 0, 0};                                        \
    int nkb = 0;                                                                \
    for (int s_ = 0; s_ < (NSEG); ++s_) nkb += (SEGS)[s_].nkb;                  \
    stage_step((SEGS), (NSEG), 0, lds[0][0], lds[0][1], (M0), (N0W),            \
               zerobuf, wid, lane);                                             \
    int cur = 0;                                                                \
    for (int kb = 0; kb < nkb; ++kb) {                                          \
        __syncthreads();                                                        \
        if (kb + 1 < nkb)                                                       \
            stage_step((SEGS), (NSEG), kb + 1, lds[cur ^ 1][0],                 \
                       lds[cur ^ 1][1], (M0), (N0W), zerobuf, wid, lane);       \
        compute_tile(acc, lds[cur][0], lds[cur][1], wr, wc, lane);              \
        cur ^= 1;                                                               \
    }

// ---------------- e = sigmoid(xw @ w_e^T + b_e), e layout [b*T+t][512] -----
__global__ __launch_bounds__(256) void ekernel(
    const u16* __restrict__ xw, const u16* __restrict__ w_e,
    const float* __restrict__ b_e, u16* __restrict__ eout)
{
    const int lane = threadIdx.x & 63;
    const int wid  = threadIdx.x >> 6;
    const int m0 = blockIdx.x * 64 + (wid >> 1) * 32;
    const int n0 = blockIdx.y * 64 + (wid & 1) * 32;
    f32x4 acc[2][2];
    acc[0][0] = f32x4{0,0,0,0}; acc[0][1] = f32x4{0,0,0,0};
    acc[1][0] = f32x4{0,0,0,0}; acc[1][1] = f32x4{0,0,0,0};
    const int l15 = lane & 15;
    const int klane = (lane >> 4) * 8;
    short8 b0 = *(const short8*)(w_e + (n0 + l15) * Wsz + klane);
    short8 b1 = *(const short8*)(w_e + (n0 + 16 + l15) * Wsz + klane);
#pragma unroll
    for (int am = 0; am < 2; ++am) {
        short8 a = *(const short8*)(xw + (long)(m0 + am * 16 + l15) * Wsz + klane);
        acc[am][0] = MF(a, b0, acc[am][0]);
        acc[am][1] = MF(a, b1, acc[am][1]);
    }
    const int col = lane & 15;
    const int r0 = (lane >> 4) * 4;
#pragma unroll
    for (int am = 0; am < 2; ++am)
#pragma unroll
        for (int bn = 0; bn < 2; ++bn)
#pragma unroll
            for (int i = 0; i < 4; ++i) {
                long row = m0 + am * 16 + r0 + i;
                int g = n0 + bn * 16 + col;
                eout[row * Hsz + g] = f2bf(sigm(acc[am][bn][i] + b_e[g]));
            }
}

// ---------------- pre-pass: writes frag-permuted prep (r9-exact) -----------
__global__ __launch_bounds__(256, 2) void prepass_kernel(
    const u16* __restrict__ x, const u16* __restrict__ e,
    const u16* __restrict__ w_d, const u16* __restrict__ w_w,
    const u16* __restrict__ w_m, const u16* __restrict__ w_rx,
    const u16* __restrict__ w_re, const u16* __restrict__ w_zx,
    const u16* __restrict__ w_ze, const u16* __restrict__ w_hx,
    const float* __restrict__ b_r, const float* __restrict__ b_z,
    const float* __restrict__ b_h,
    const u16* __restrict__ zerobuf, u16* __restrict__ prep)
{
    const int m0 = blockIdx.x * 128;
    const int y = blockIdx.y;
    const int group = y >> 2;
    const int nin = (y & 3) * 128;
    Seg segs[3];
    int nseg;
    const float* bias = nullptr;
    if (group == 0) {
        segs[0] = { x, Isz, -1 * Tsz,  w_d, Isz, Isz / 64 };
        segs[1] = { x, Isz, -7 * Tsz,  w_w, Isz, Isz / 64 };
        segs[2] = { x, Isz, -30 * Tsz, w_m, Isz, Isz / 64 };
        nseg = 3;
    } else if (group == 1) {
        segs[0] = { x, Isz, 0, w_rx, Isz, Isz / 64 };
        segs[1] = { e, Hsz, 0, w_re, Hsz, Hsz / 64 };
        nseg = 2; bias = b_r;
    } else if (group == 2) {
        segs[0] = { x, Isz, 0, w_zx, Isz, Isz / 64 };
        segs[1] = { e, Hsz, 0, w_ze, Hsz, Hsz / 64 };
        nseg = 2; bias = b_z;
    } else {
        segs[0] = { x, Isz, 0, w_hx, Isz, Isz / 64 };
        nseg = 1; bias = b_h;
    }
    GEMM_CORE(segs, nseg, m0, nin)
    const int l15 = lane & 15, hi4v = (lane >> 4) * 4;
#pragma unroll
    for (int am = 0; am < 4; ++am)
#pragma unroll
        for (int bn = 0; bn < 4; ++bn) {
            int colH = nin + wc * 64 + bn * 16 + l15;
            float bv = bias ? bias[colH] : 0.0f;
            int wv = colH >> 5, ntv = (colH >> 4) & 1, l15v = colH & 15;
#pragma unroll
            for (int i = 0; i < 4; ++i) {
                long m = m0 + wr * 64 + am * 16 + hi4v + i;
                int b = (int)(m / Tsz), t = (int)(m % Tsz);
                int bblk = b >> 4, rowin = b & 15;
                int hiv = rowin >> 2, iv = rowin & 3;
                long idx = (((long)(bblk * Tsz + t) * 4 + group) * 16 + wv) * 512
                           + (hiv * 16 + l15v) * 8 + ntv * 4 + iv;
                prep[idx] = f2bf(acc[am][bn][i] + bv);
            }
        }
}

// ======================= persistent recurrence =============================
// r12 structure exactly (double-buffered __syncthreads chunk pipeline),
// with ONLY the weight-buffer layout swapped to the r13-verified
// beat-conflict-free mapping:
//   granule (col,sub) stored at slot (col>>1)*8 + ((sub+4*(col&1)) ^
//   ((col>>1)&7)); pre-swizzled global source, linear LDS dest (rule #21).
// Each 8-lane read beat covers all 8 bank-groups (2-way alias only).
#define SROW 528

__device__ __forceinline__ int swz(int row, int col) {
    return row * SROW + ((((col >> 3) ^ (row & 7)) << 3) | (col & 7));
}

// stage chunk c of Wm (512 cols x 32 k) into 32KB buf; wave covers slots
// [wave*128, wave*128+128). Source pre-swizzled for the slot mapping above.
__device__ __forceinline__ void stage_chunk(
    const u16* __restrict__ Wm, int c, u16* buf, int wave, int lane)
{
    int s1 = wave * 128 + lane;
    int s2 = s1 + 64;
    int p1 = s1 >> 3, g1 = (s1 & 7) ^ (p1 & 7);
    int p2 = s2 >> 3, g2 = (s2 & 7) ^ (p2 & 7);
    GLOAD_LDS16(Wm + (long)(2 * p1 + (g1 >> 2)) * 512 + c * 32 + (g1 & 3) * 8,
                buf + wave * 1024);
    GLOAD_LDS16(Wm + (long)(2 * p2 + (g2 >> 2)) * 512 + c * 32 + (g2 & 3) * 8,
                buf + wave * 1024 + 512);
}

// one staged pass: acc[2] += state(16x512 LDS) @ Wm cols [n0,n0+32)
__device__ __forceinline__ void wpass_staged(
    f32x4 acc[2], const u16* aS, const u16* __restrict__ Wm,
    u16* wbuf0, u16* wbuf1, int n0, int l15, int hi, int wave, int lane)
{
    const int rx = l15 & 7;
    const u16* ap = aS + l15 * SROW;
    // read offset for col n0+l15, sub hi (slot mapping above); col+16 -> +512
    const int bo0 = (wave * 128 + (l15 >> 1) * 8
                     + ((hi + 4 * (l15 & 1)) ^ (l15 >> 1))) * 8;
    stage_chunk(Wm, 0, wbuf0, wave, lane);
#pragma unroll 1
    for (int c = 0; c < 16; ++c) {
        __syncthreads();              // chunk c resident (vmcnt drain + bar)
        u16* cur = (c & 1) ? wbuf1 : wbuf0;
        u16* nxt = (c & 1) ? wbuf0 : wbuf1;
        if (c < 15) stage_chunk(Wm, c + 1, nxt, wave, lane);
        short8 b0 = *(const short8*)(cur + bo0);
        short8 b1 = *(const short8*)(cur + bo0 + 512);
        short8 a = *(const short8*)(ap + (((c * 4 + hi) ^ rx) << 3));
        acc[0] = MF(a, b0, acc[0]);
        acc[1] = MF(a, b1, acc[1]);
    }
}

#define FOR_FRAG \
    _Pragma("unroll") for (int nt2 = 0; nt2 < 2; ++nt2) \
    _Pragma("unroll") for (int i = 0; i < 4; ++i)

__global__ __launch_bounds__(1024, 4) void rnn_kernel(
    const u16* __restrict__ prep, const u16* __restrict__ w_t_,
    const u16* __restrict__ w_rh, const u16* __restrict__ w_zh,
    const u16* __restrict__ w_hh, float* __restrict__ out)
{
    __shared__ __align__(16) u16 hS[16 * SROW];
    __shared__ __align__(16) u16 hoS[16 * SROW];
    __shared__ __align__(16) u16 rhS[16 * SROW];
    __shared__ __align__(16) u16 wbuf0[16 * 1024];   // 32KB chunk buf A
    __shared__ __align__(16) u16 wbuf1[16 * 1024];   // 32KB chunk buf B
    const int tid = threadIdx.x;
    const int lane = tid & 63;
    const int wave = tid >> 6;
    const int l15 = lane & 15, hi = lane >> 4;
    const int n0 = wave * 32;
    const long b0 = (long)blockIdx.x * 16;

    for (int i = tid * 8; i < 16 * SROW; i += 1024 * 8)
        *(short8*)(hS + i) = (short8)0;
    __syncthreads();

    const u16* pbase = prep + (long)blockIdx.x * (Tsz * 4 * 8192)
                       + wave * 512 + lane * 8;

#pragma unroll 1
    for (int t = 0; t < Tsz; ++t) {
        const u16* pt = pbase + (long)t * 4 * 8192;
        short8 po = ntload8(pt);

        // ---- stage A: ho = sigm(pre_o + h @ w_t^T) ----
        f32x4 accO[2];
        accO[0] = f32x4{0,0,0,0}; accO[1] = f32x4{0,0,0,0};
        wpass_staged(accO, hS, w_t_, wbuf0, wbuf1, n0, l15, hi, wave, lane);
        float hov[2][4];
        FOR_FRAG {
            float v = sigm(accO[nt2][i] + bf2f((u16)po[nt2 * 4 + i]));
            hov[nt2][i] = v;
            hoS[swz(hi * 4 + i, n0 + nt2 * 16 + l15)] = f2bf(v);
        }
        // hoS visible at next pass's first barrier

        // ---- stage B: r,z = sigm(pre + ho @ w^T); rh = r*ho -> rhS ----
        short8 pr = ntload8(pt + 8192);
        short8 pz = ntload8(pt + 2 * 8192);
        f32x4 accR[2];
        accR[0] = f32x4{0,0,0,0}; accR[1] = f32x4{0,0,0,0};
        wpass_staged(accR, hoS, w_rh, wbuf0, wbuf1, n0, l15, hi, wave, lane);
        f32x4 accZ[2];
        accZ[0] = f32x4{0,0,0,0}; accZ[1] = f32x4{0,0,0,0};
        wpass_staged(accZ, hoS, w_zh, wbuf0, wbuf1, n0, l15, hi, wave, lane);
        float zv[2][4];
        FOR_FRAG {
            zv[nt2][i] = sigm(accZ[nt2][i] + bf2f((u16)pz[nt2 * 4 + i]));
            float rv = sigm(accR[nt2][i] + bf2f((u16)pr[nt2 * 4 + i]));
            rhS[swz(hi * 4 + i, n0 + nt2 * 16 + l15)] = f2bf(rv * hov[nt2][i]);
        }

        // ---- stage C: h~ = tanh(pre_h + rh @ w_hh^T); h = (1-z)ho + z h~ ----
        short8 ph = ntload8(pt + 3 * 8192);
        f32x4 accH[2];
        accH[0] = f32x4{0,0,0,0}; accH[1] = f32x4{0,0,0,0};
        wpass_staged(accH, rhS, w_hh, wbuf0, wbuf1, n0, l15, hi, wave, lane);
        FOR_FRAG {
            int row = hi * 4 + i, col = n0 + nt2 * 16 + l15;
            float htl = tanhf(accH[nt2][i] + bf2f((u16)ph[nt2 * 4 + i]));
            float z = zv[nt2][i];
            float hn = (1.0f - z) * hov[nt2][i] + z * htl;
            __builtin_nontemporal_store(
                hn, &out[((b0 + row) * Tsz + t) * (long)Hsz + col]);
            hS[swz(row, col)] = f2bf(hn);
        }
        __syncthreads();  // hS complete before next step's A-pass staging
    }
}

extern "C" void kernel_launch(void* const* d_in, const int* in_sizes, int n_in,
                              void* d_out, int out_size, void* d_ws, size_t ws_size,
                              hipStream_t stream) {
    const float* x_f    = (const float*)d_in[0];
    const float* xw_f   = (const float*)d_in[1];
    const float* w_rx_f = (const float*)d_in[2];
    const float* w_rh_f = (const float*)d_in[3];
    const float* w_re_f = (const float*)d_in[4];
    const float* b_r    = (const float*)d_in[5];
    const float* w_zx_f = (const float*)d_in[6];
    const float* w_zh_f = (const float*)d_in[7];
    const float* w_ze_f = (const float*)d_in[8];
    const float* b_z    = (const float*)d_in[9];
    const float* w_hx_f = (const float*)d_in[10];
    const float* w_hh_f = (const float*)d_in[11];
    const float* b_h    = (const float*)d_in[12];
    const float* w_d_f  = (const float*)d_in[13];
    const float* w_w_f  = (const float*)d_in[14];
    const float* w_m_f  = (const float*)d_in[15];
    const float* w_t_f  = (const float*)d_in[16];
    const float* w_e_f  = (const float*)d_in[17];
    const float* b_e    = (const float*)d_in[18];
    float* out = (float*)d_out;

    char* ws = (char*)d_ws;
    size_t off = 0;
    auto alloc = [&](size_t bytes) {
        size_t o = off; off = (off + bytes + 255) & ~(size_t)255; return o;
    };
    const size_t nx  = (size_t)Msz * Isz;
    const size_t nxw = (size_t)Msz * Wsz;

    u16* x_bf  = (u16*)(ws + alloc(nx * 2));
    u16* xw_bf = (u16*)(ws + alloc(nxw * 2));
    u16* w_rx  = (u16*)(ws + alloc(Hsz * Isz * 2));
    u16* w_rh  = (u16*)(ws + alloc(Hsz * Hsz * 2));
    u16* w_re  = (u16*)(ws + alloc(Hsz * Hsz * 2));
    u16* w_zx  = (u16*)(ws + alloc(Hsz * Isz * 2));
    u16* w_zh  = (u16*)(ws + alloc(Hsz * Hsz * 2));
    u16* w_ze  = (u16*)(ws + alloc(Hsz * Hsz * 2));
    u16* w_hx  = (u16*)(ws + alloc(Hsz * Isz * 2));
    u16* w_hh  = (u16*)(ws + alloc(Hsz * Hsz * 2));
    u16* w_d   = (u16*)(ws + alloc(Hsz * Isz * 2));
    u16* w_w   = (u16*)(ws + alloc(Hsz * Isz * 2));
    u16* w_m   = (u16*)(ws + alloc(Hsz * Isz * 2));
    u16* w_t   = (u16*)(ws + alloc(Hsz * Hsz * 2));
    u16* w_e   = (u16*)(ws + alloc(Hsz * Wsz * 2));
    u16* e_bf  = (u16*)(ws + alloc((size_t)Msz * Hsz * 2));   // 96 MB [b*T+t]
    u16* prep  = (u16*)(ws + alloc((size_t)Msz * 2048 * 2));  // 384 MB permuted
    u16* zerobuf = (u16*)(ws + alloc(256));

    convert_big<<<(int)(nx / 1024), 256, 0, stream>>>(x_f, x_bf, (int)nx);
    convert_big<<<(int)(nxw / 1024), 256, 0, stream>>>(xw_f, xw_bf, (int)nxw);
    ConvTab tab;
    tab.d[0]  = { w_rx_f, w_rx, Hsz * Isz };
    tab.d[1]  = { w_rh_f, w_rh, Hsz * Hsz };
    tab.d[2]  = { w_re_f, w_re, Hsz * Hsz };
    tab.d[3]  = { w_zx_f, w_zx, Hsz * Isz };
    tab.d[4]  = { w_zh_f, w_zh, Hsz * Hsz };
    tab.d[5]  = { w_ze_f, w_ze, Hsz * Hsz };
    tab.d[6]  = { w_hx_f, w_hx, Hsz * Isz };
    tab.d[7]  = { w_hh_f, w_hh, Hsz * Hsz };
    tab.d[8]  = { w_d_f,  w_d,  Hsz * Isz };
    tab.d[9]  = { w_w_f,  w_w,  Hsz * Isz };
    tab.d[10] = { w_m_f,  w_m,  Hsz * Isz };
    tab.d[11] = { w_t_f,  w_t,  Hsz * Hsz };
    tab.d[12] = { w_e_f,  w_e,  Hsz * Wsz };
    convert_many<<<dim3(256, 13), 256, 0, stream>>>(tab);
    hipMemsetAsync(zerobuf, 0, 256, stream);

    // e = sigmoid(xw @ w_e^T + b_e)  [98304 x 512], layout [b*T+t]
    ekernel<<<dim3(Msz / 64, Hsz / 64), 256, 0, stream>>>(xw_bf, w_e, b_e, e_bf);

    // pre-pass: all input-only projections, frag-permuted output
    prepass_kernel<<<dim3(Msz / 128, 16), 256, 0, stream>>>(
        x_bf, e_bf, w_d, w_w, w_m, w_rx, w_re, w_zx, w_ze, w_hx,
        b_r, b_z, b_h, zerobuf, prep);

    // persistent recurrence: 256 blocks x 16 waves, staged weights
    // (r12 schedule, r13-verified conflict-free weight-buffer layout)
    rnn_kernel<<<Bsz / 16, 1024, 0, stream>>>(prep, w_t, w_rh, w_zh, w_hh, out);
}

// Round 15
// 1597.346 us; speedup vs baseline: 2.1491x; 1.0850x over previous
//
#include <hip/hip_runtime.h>
#include <stdint.h>

#define Bsz 4096
#define Tsz 24
#define Isz 128
#define Hsz 512
#define Wsz 32
#define Msz (Bsz * Tsz)   // 98304 flat rows (b*T+t)

typedef __attribute__((ext_vector_type(8))) short short8;
typedef __attribute__((ext_vector_type(4))) float f32x4;
typedef unsigned short u16;

__device__ __forceinline__ float bf2f(u16 u) {
    union { unsigned int i; float f; } v; v.i = ((unsigned int)u) << 16; return v.f;
}
__device__ __forceinline__ u16 f2bf(float f) {
    union { float f; unsigned int i; } v; v.f = f;
    unsigned int r = v.i + 0x7fffu + ((v.i >> 16) & 1u);
    return (u16)(r >> 16);
}
__device__ __forceinline__ float sigm(float x) { return 1.0f / (1.0f + expf(-x)); }

__device__ __forceinline__ f32x4 MF(short8 a, short8 b, f32x4 c) {
    return __builtin_amdgcn_mfma_f32_16x16x32_bf16(a, b, c, 0, 0, 0);
}
__device__ __forceinline__ short8 ntload8(const u16* p) {
    return __builtin_nontemporal_load((const short8*)p);
}

#define GLOAD_LDS16(SRC, DST) \
    __builtin_amdgcn_global_load_lds( \
        (__attribute__((address_space(1))) void*)(SRC), \
        (__attribute__((address_space(3))) void*)(DST), 16, 0, 0)

// ---------------- f32 -> bf16 conversion ----------------------------------
__global__ __launch_bounds__(256) void convert_big(
    const float* __restrict__ src, u16* __restrict__ dst, int n)
{
    int i = (blockIdx.x * 256 + threadIdx.x) * 4;
    if (i + 4 <= n) {
        float4 v = *(const float4*)(src + i);
        dst[i + 0] = f2bf(v.x); dst[i + 1] = f2bf(v.y);
        dst[i + 2] = f2bf(v.z); dst[i + 3] = f2bf(v.w);
    }
}

struct ConvDesc { const float* src; u16* dst; int n; };
struct ConvTab { ConvDesc d[13]; };

__global__ __launch_bounds__(256) void convert_many(ConvTab tab)
{
    ConvDesc cd = tab.d[blockIdx.y];
    for (int i = (blockIdx.x * 256 + threadIdx.x) * 4; i < cd.n;
         i += gridDim.x * 256 * 4) {
        float4 v = *(const float4*)(cd.src + i);
        cd.dst[i + 0] = f2bf(v.x); cd.dst[i + 1] = f2bf(v.y);
        cd.dst[i + 2] = f2bf(v.z); cd.dst[i + 3] = f2bf(v.w);
    }
}

// ======================= prepass GEMM machinery (r5-exact) =================
struct Seg { const u16* A; int astr; int shift; const u16* W; int wstr; int nkb; };

__device__ __forceinline__ void stage_half(
    u16* ldsT, const u16* gbase, int rstr, int rvf,
    const u16* zerobuf, int wid, int lane)
{
#pragma unroll
    for (int q = 0; q < 4; ++q) {
        int c   = wid * 4 + q;
        int lin = c * 64 + lane;
        int row = lin >> 3;
        int gc  = lin & 7;
        const u16* src = (row >= rvf)
            ? (gbase + (long)row * rstr + ((gc ^ (row & 7)) << 3))
            : zerobuf;
        GLOAD_LDS16(src, ldsT + c * 512);
    }
}

__device__ __forceinline__ void stage_step(
    const Seg* segs, int nseg, int kb, u16* ldsA, u16* ldsB,
    int m0, int n0, const u16* zerobuf, int wid, int lane)
{
    Seg s = segs[0];
    int kloc = kb;
    if (nseg > 1 && kloc >= s.nkb) {
        kloc -= s.nkb; s = segs[1];
        if (nseg > 2 && kloc >= s.nkb) { kloc -= s.nkb; s = segs[2]; }
    }
    int base_row = m0 + s.shift;
    int rvf = base_row < 0 ? -base_row : 0;
    stage_half(ldsA, s.A + (long)base_row * s.astr + kloc * 64, s.astr, rvf,
               zerobuf, wid, lane);
    stage_half(ldsB, s.W + (long)n0 * s.wstr + kloc * 64, s.wstr, 0,
               zerobuf, wid, lane);
}

__device__ __forceinline__ void compute_tile(
    f32x4 acc[4][4], const u16* Ab, const u16* Bb, int wr, int wc, int lane)
{
    const int l15 = lane & 15;
    const int hi = lane >> 4;
#pragma unroll
    for (int ks = 0; ks < 2; ++ks) {
        int kg = ks * 4 + hi;
        short8 a[4], b[4];
#pragma unroll
        for (int am = 0; am < 4; ++am) {
            int row = wr * 64 + am * 16 + l15;
            a[am] = *(const short8*)(Ab + row * 64 + ((kg ^ (row & 7)) << 3));
        }
#pragma unroll
        for (int bn = 0; bn < 4; ++bn) {
            int row = wc * 64 + bn * 16 + l15;
            b[bn] = *(const short8*)(Bb + row * 64 + ((kg ^ (row & 7)) << 3));
        }
#pragma unroll
        for (int am = 0; am < 4; ++am)
#pragma unroll
            for (int bn = 0; bn < 4; ++bn)
                acc[am][bn] = MF(a[am], b[bn], acc[am][bn]);
    }
}

#define GEMM_CORE(SEGS, NSEG, M0, N0W)                                          \
    __shared__ u16 lds[2][2][128 * 64];                                         \
    const int lane = threadIdx.x & 63;                                          \
    const int wid  = threadIdx.x >> 6;                                          \
    const int wr = wid >> 1, wc = wid & 1;                                      \
    f32x4 acc[4][4];                                                            \
    _Pragma("unroll") for (int i_ = 0; i_ < 4; ++i_)                            \
    _Pragma("unroll") for (int j_ = 0; j_ < 4; ++j_)                            \
        acc[i_][j_] = f32x4{0, 0, 0, 0};                                        \
    int nkb = 0;                                                                \
    for (int s_ = 0; s_ < (NSEG); ++s_) nkb += (SEGS)[s_].nkb;                  \
    stage_step((SEGS), (NSEG), 0, lds[0][0], lds[0][1], (M0), (N0W),            \
               zerobuf, wid, lane);                                             \
    int cur = 0;                                                                \
    for (int kb = 0; kb < nkb; ++kb) {                                          \
        __syncthreads();                                                        \
        if (kb + 1 < nkb)                                                       \
            stage_step((SEGS), (NSEG), kb + 1, lds[cur ^ 1][0],                 \
                       lds[cur ^ 1][1], (M0), (N0W), zerobuf, wid, lane);       \
        compute_tile(acc, lds[cur][0], lds[cur][1], wr, wc, lane);              \
        cur ^= 1;                                                               \
    }

// ---------------- e = sigmoid(xw @ w_e^T + b_e), e layout [b*T+t][512] -----
__global__ __launch_bounds__(256) void ekernel(
    const u16* __restrict__ xw, const u16* __restrict__ w_e,
    const float* __restrict__ b_e, u16* __restrict__ eout)
{
    const int lane = threadIdx.x & 63;
    const int wid  = threadIdx.x >> 6;
    const int m0 = blockIdx.x * 64 + (wid >> 1) * 32;
    const int n0 = blockIdx.y * 64 + (wid & 1) * 32;
    f32x4 acc[2][2];
    acc[0][0] = f32x4{0,0,0,0}; acc[0][1] = f32x4{0,0,0,0};
    acc[1][0] = f32x4{0,0,0,0}; acc[1][1] = f32x4{0,0,0,0};
    const int l15 = lane & 15;
    const int klane = (lane >> 4) * 8;
    short8 b0 = *(const short8*)(w_e + (n0 + l15) * Wsz + klane);
    short8 b1 = *(const short8*)(w_e + (n0 + 16 + l15) * Wsz + klane);
#pragma unroll
    for (int am = 0; am < 2; ++am) {
        short8 a = *(const short8*)(xw + (long)(m0 + am * 16 + l15) * Wsz + klane);
        acc[am][0] = MF(a, b0, acc[am][0]);
        acc[am][1] = MF(a, b1, acc[am][1]);
    }
    const int col = lane & 15;
    const int r0 = (lane >> 4) * 4;
#pragma unroll
    for (int am = 0; am < 2; ++am)
#pragma unroll
        for (int bn = 0; bn < 2; ++bn)
#pragma unroll
            for (int i = 0; i < 4; ++i) {
                long row = m0 + am * 16 + r0 + i;
                int g = n0 + bn * 16 + col;
                eout[row * Hsz + g] = f2bf(sigm(acc[am][bn][i] + b_e[g]));
            }
}

// ---------------- pre-pass: writes frag-permuted prep (r9-exact) -----------
__global__ __launch_bounds__(256, 2) void prepass_kernel(
    const u16* __restrict__ x, const u16* __restrict__ e,
    const u16* __restrict__ w_d, const u16* __restrict__ w_w,
    const u16* __restrict__ w_m, const u16* __restrict__ w_rx,
    const u16* __restrict__ w_re, const u16* __restrict__ w_zx,
    const u16* __restrict__ w_ze, const u16* __restrict__ w_hx,
    const float* __restrict__ b_r, const float* __restrict__ b_z,
    const float* __restrict__ b_h,
    const u16* __restrict__ zerobuf, u16* __restrict__ prep)
{
    const int m0 = blockIdx.x * 128;
    const int y = blockIdx.y;
    const int group = y >> 2;
    const int nin = (y & 3) * 128;
    Seg segs[3];
    int nseg;
    const float* bias = nullptr;
    if (group == 0) {
        segs[0] = { x, Isz, -1 * Tsz,  w_d, Isz, Isz / 64 };
        segs[1] = { x, Isz, -7 * Tsz,  w_w, Isz, Isz / 64 };
        segs[2] = { x, Isz, -30 * Tsz, w_m, Isz, Isz / 64 };
        nseg = 3;
    } else if (group == 1) {
        segs[0] = { x, Isz, 0, w_rx, Isz, Isz / 64 };
        segs[1] = { e, Hsz, 0, w_re, Hsz, Hsz / 64 };
        nseg = 2; bias = b_r;
    } else if (group == 2) {
        segs[0] = { x, Isz, 0, w_zx, Isz, Isz / 64 };
        segs[1] = { e, Hsz, 0, w_ze, Hsz, Hsz / 64 };
        nseg = 2; bias = b_z;
    } else {
        segs[0] = { x, Isz, 0, w_hx, Isz, Isz / 64 };
        nseg = 1; bias = b_h;
    }
    GEMM_CORE(segs, nseg, m0, nin)
    const int l15 = lane & 15, hi4v = (lane >> 4) * 4;
#pragma unroll
    for (int am = 0; am < 4; ++am)
#pragma unroll
        for (int bn = 0; bn < 4; ++bn) {
            int colH = nin + wc * 64 + bn * 16 + l15;
            float bv = bias ? bias[colH] : 0.0f;
            int wv = colH >> 5, ntv = (colH >> 4) & 1, l15v = colH & 15;
#pragma unroll
            for (int i = 0; i < 4; ++i) {
                long m = m0 + wr * 64 + am * 16 + hi4v + i;
                int b = (int)(m / Tsz), t = (int)(m % Tsz);
                int bblk = b >> 4, rowin = b & 15;
                int hiv = rowin >> 2, iv = rowin & 3;
                long idx = (((long)(bblk * Tsz + t) * 4 + group) * 16 + wv) * 512
                           + (hiv * 16 + l15v) * 8 + ntv * 4 + iv;
                prep[idx] = f2bf(acc[am][bn][i] + bv);
            }
        }
}

// ======================= persistent recurrence =============================
// 256 blocks x 1024 thr (16 waves). Block owns 16 batch rows. Wave owns 32
// output cols. Weights staged global->LDS in 64KB K=64 chunks (8 iterations
// per pass, r12 double-buffered __syncthreads schedule). Weight buffer =
// two 32KB halves, each with the r14-verified beat-conflict-free mapping:
//   granule (col,sub) at slot (col>>1)*8 + ((sub+4*(col&1)) ^ ((col>>1)&7)).
// Single state array hS (16x528): h, ho, rh time-share it with
// write-after-read barriers (h dead after pass A, ho dead after pass Z,
// rh dead after pass H); visibility via each next pass's first barrier.
#define SROW 528

__device__ __forceinline__ int swz(int row, int col) {
    return row * SROW + ((((col >> 3) ^ (row & 7)) << 3) | (col & 7));
}

// stage chunk c (512 cols x 64 k) into 64KB buf (two 32KB halves);
// wave covers slots [wave*128, wave*128+128) of each half (4 loads/lane).
__device__ __forceinline__ void stage_chunk64(
    const u16* __restrict__ Wm, int c, u16* buf, int wave, int lane)
{
    int s1 = wave * 128 + lane;
    int s2 = s1 + 64;
    int p1 = s1 >> 3, g1 = (s1 & 7) ^ (p1 & 7);
    int p2 = s2 >> 3, g2 = (s2 & 7) ^ (p2 & 7);
#pragma unroll
    for (int h = 0; h < 2; ++h) {
        GLOAD_LDS16(Wm + (long)(2 * p1 + (g1 >> 2)) * 512
                       + c * 64 + h * 32 + (g1 & 3) * 8,
                    buf + h * 16384 + wave * 1024);
        GLOAD_LDS16(Wm + (long)(2 * p2 + (g2 >> 2)) * 512
                       + c * 64 + h * 32 + (g2 & 3) * 8,
                    buf + h * 16384 + wave * 1024 + 512);
    }
}

// one staged pass: acc[2] += state(16x512 LDS) @ Wm cols [n0,n0+32)
__device__ __forceinline__ void wpass_staged(
    f32x4 acc[2], const u16* aS, const u16* __restrict__ Wm,
    u16* wbuf0, u16* wbuf1, int bo0, int rx, int l15, int hi,
    int wave, int lane)
{
    const u16* ap = aS + l15 * SROW;
    stage_chunk64(Wm, 0, wbuf0, wave, lane);
#pragma unroll 1
    for (int c = 0; c < 8; ++c) {
        __syncthreads();              // chunk c resident (vmcnt drain + bar)
        u16* cur = (c & 1) ? wbuf1 : wbuf0;
        u16* nxt = (c & 1) ? wbuf0 : wbuf1;
        if (c < 7) stage_chunk64(Wm, c + 1, nxt, wave, lane);
#pragma unroll
        for (int kk = 0; kk < 2; ++kk) {
            short8 b0 = *(const short8*)(cur + kk * 16384 + bo0);
            short8 b1 = *(const short8*)(cur + kk * 16384 + bo0 + 512);
            short8 a = *(const short8*)(
                ap + ((((c * 2 + kk) * 4 + hi) ^ rx) << 3));
            acc[0] = MF(a, b0, acc[0]);
            acc[1] = MF(a, b1, acc[1]);
        }
    }
}

#define FOR_FRAG \
    _Pragma("unroll") for (int nt2 = 0; nt2 < 2; ++nt2) \
    _Pragma("unroll") for (int i = 0; i < 4; ++i)

__global__ __launch_bounds__(1024, 4) void rnn_kernel(
    const u16* __restrict__ prep, const u16* __restrict__ w_t_,
    const u16* __restrict__ w_rh, const u16* __restrict__ w_zh,
    const u16* __restrict__ w_hh, float* __restrict__ out)
{
    __shared__ __align__(16) u16 hS[16 * SROW];        // h / ho / rh
    __shared__ __align__(16) u16 wbuf0[32 * 1024];     // 64KB chunk buf A
    __shared__ __align__(16) u16 wbuf1[32 * 1024];     // 64KB chunk buf B
    const int tid = threadIdx.x;
    const int lane = tid & 63;
    const int wave = tid >> 6;
    const int l15 = lane & 15, hi = lane >> 4;
    const int rx = l15 & 7;
    const int n0 = wave * 32;
    const long b0 = (long)blockIdx.x * 16;
    // weight-buffer read offset for col n0+l15, sub hi; col+16 -> +512
    const int bo0 = (wave * 128 + (l15 >> 1) * 8
                     + ((hi + 4 * (l15 & 1)) ^ (l15 >> 1))) * 8;

    for (int i = tid * 8; i < 16 * SROW; i += 1024 * 8)
        *(short8*)(hS + i) = (short8)0;
    __syncthreads();

    const u16* pbase = prep + (long)blockIdx.x * (Tsz * 4 * 8192)
                       + wave * 512 + lane * 8;

#pragma unroll 1
    for (int t = 0; t < Tsz; ++t) {
        const u16* pt = pbase + (long)t * 4 * 8192;
        short8 po = ntload8(pt);

        // ---- stage A: ho = sigm(pre_o + h @ w_t^T)  [reads hS = h] ----
        f32x4 accO[2];
        accO[0] = f32x4{0,0,0,0}; accO[1] = f32x4{0,0,0,0};
        wpass_staged(accO, hS, w_t_, wbuf0, wbuf1, bo0, rx, l15, hi,
                     wave, lane);
        float hov[2][4];
        FOR_FRAG {
            float v = sigm(accO[nt2][i] + bf2f((u16)po[nt2 * 4 + i]));
            hov[nt2][i] = v;
        }
        __syncthreads();   // all waves done reading hS(=h)
        FOR_FRAG hS[swz(hi * 4 + i, n0 + nt2 * 16 + l15)] = f2bf(hov[nt2][i]);
        // visibility via pass R's first internal barrier

        // ---- stage B: r,z = sigm(pre + ho @ w^T)  [reads hS = ho] ----
        short8 pr = ntload8(pt + 8192);
        short8 pz = ntload8(pt + 2 * 8192);
        f32x4 accR[2];
        accR[0] = f32x4{0,0,0,0}; accR[1] = f32x4{0,0,0,0};
        wpass_staged(accR, hS, w_rh, wbuf0, wbuf1, bo0, rx, l15, hi,
                     wave, lane);
        f32x4 accZ[2];
        accZ[0] = f32x4{0,0,0,0}; accZ[1] = f32x4{0,0,0,0};
        wpass_staged(accZ, hS, w_zh, wbuf0, wbuf1, bo0, rx, l15, hi,
                     wave, lane);
        float zv[2][4], rhv[2][4];
        FOR_FRAG {
            zv[nt2][i] = sigm(accZ[nt2][i] + bf2f((u16)pz[nt2 * 4 + i]));
            float rv = sigm(accR[nt2][i] + bf2f((u16)pr[nt2 * 4 + i]));
            rhv[nt2][i] = rv * hov[nt2][i];
        }
        __syncthreads();   // all waves done reading hS(=ho)
        FOR_FRAG hS[swz(hi * 4 + i, n0 + nt2 * 16 + l15)] = f2bf(rhv[nt2][i]);
        // visibility via pass H's first internal barrier

        // ---- stage C: h~ = tanh(pre_h + rh @ w_hh^T)  [reads hS = rh] ----
        short8 ph = ntload8(pt + 3 * 8192);
        f32x4 accH[2];
        accH[0] = f32x4{0,0,0,0}; accH[1] = f32x4{0,0,0,0};
        wpass_staged(accH, hS, w_hh, wbuf0, wbuf1, bo0, rx, l15, hi,
                     wave, lane);
        __syncthreads();   // all waves done reading hS(=rh)
        FOR_FRAG {
            int row = hi * 4 + i, col = n0 + nt2 * 16 + l15;
            float htl = tanhf(accH[nt2][i] + bf2f((u16)ph[nt2 * 4 + i]));
            float z = zv[nt2][i];
            float hn = (1.0f - z) * hov[nt2][i] + z * htl;
            __builtin_nontemporal_store(
                hn, &out[((b0 + row) * Tsz + t) * (long)Hsz + col]);
            hS[swz(row, col)] = f2bf(hn);
        }
        // h_next visibility via next step's pass A first internal barrier
    }
}

extern "C" void kernel_launch(void* const* d_in, const int* in_sizes, int n_in,
                              void* d_out, int out_size, void* d_ws, size_t ws_size,
                              hipStream_t stream) {
    const float* x_f    = (const float*)d_in[0];
    const float* xw_f   = (const float*)d_in[1];
    const float* w_rx_f = (const float*)d_in[2];
    const float* w_rh_f = (const float*)d_in[3];
    const float* w_re_f = (const float*)d_in[4];
    const float* b_r    = (const float*)d_in[5];
    const float* w_zx_f = (const float*)d_in[6];
    const float* w_zh_f = (const float*)d_in[7];
    const float* w_ze_f = (const float*)d_in[8];
    const float* b_z    = (const float*)d_in[9];
    const float* w_hx_f = (const float*)d_in[10];
    const float* w_hh_f = (const float*)d_in[11];
    const float* b_h    = (const float*)d_in[12];
    const float* w_d_f  = (const float*)d_in[13];
    const float* w_w_f  = (const float*)d_in[14];
    const float* w_m_f  = (const float*)d_in[15];
    const float* w_t_f  = (const float*)d_in[16];
    const float* w_e_f  = (const float*)d_in[17];
    const float* b_e    = (const float*)d_in[18];
    float* out = (float*)d_out;

    char* ws = (char*)d_ws;
    size_t off = 0;
    auto alloc = [&](size_t bytes) {
        size_t o = off; off = (off + bytes + 255) & ~(size_t)255; return o;
    };
    const size_t nx  = (size_t)Msz * Isz;
    const size_t nxw = (size_t)Msz * Wsz;

    u16* x_bf  = (u16*)(ws + alloc(nx * 2));
    u16* xw_bf = (u16*)(ws + alloc(nxw * 2));
    u16* w_rx  = (u16*)(ws + alloc(Hsz * Isz * 2));
    u16* w_rh  = (u16*)(ws + alloc(Hsz * Hsz * 2));
    u16* w_re  = (u16*)(ws + alloc(Hsz * Hsz * 2));
    u16* w_zx  = (u16*)(ws + alloc(Hsz * Isz * 2));
    u16* w_zh  = (u16*)(ws + alloc(Hsz * Hsz * 2));
    u16* w_ze  = (u16*)(ws + alloc(Hsz * Hsz * 2));
    u16* w_hx  = (u16*)(ws + alloc(Hsz * Isz * 2));
    u16* w_hh  = (u16*)(ws + alloc(Hsz * Hsz * 2));
    u16* w_d   = (u16*)(ws + alloc(Hsz * Isz * 2));
    u16* w_w   = (u16*)(ws + alloc(Hsz * Isz * 2));
    u16* w_m   = (u16*)(ws + alloc(Hsz * Isz * 2));
    u16* w_t   = (u16*)(ws + alloc(Hsz * Hsz * 2));
    u16* w_e   = (u16*)(ws + alloc(Hsz * Wsz * 2));
    u16* e_bf  = (u16*)(ws + alloc((size_t)Msz * Hsz * 2));   // 96 MB [b*T+t]
    u16* prep  = (u16*)(ws + alloc((size_t)Msz * 2048 * 2));  // 384 MB permuted
    u16* zerobuf = (u16*)(ws + alloc(256));

    convert_big<<<(int)(nx / 1024), 256, 0, stream>>>(x_f, x_bf, (int)nx);
    convert_big<<<(int)(nxw / 1024), 256, 0, stream>>>(xw_f, xw_bf, (int)nxw);
    ConvTab tab;
    tab.d[0]  = { w_rx_f, w_rx, Hsz * Isz };
    tab.d[1]  = { w_rh_f, w_rh, Hsz * Hsz };
    tab.d[2]  = { w_re_f, w_re, Hsz * Hsz };
    tab.d[3]  = { w_zx_f, w_zx, Hsz * Isz };
    tab.d[4]  = { w_zh_f, w_zh, Hsz * Hsz };
    tab.d[5]  = { w_ze_f, w_ze, Hsz * Hsz };
    tab.d[6]  = { w_hx_f, w_hx, Hsz * Isz };
    tab.d[7]  = { w_hh_f, w_hh, Hsz * Hsz };
    tab.d[8]  = { w_d_f,  w_d,  Hsz * Isz };
    tab.d[9]  = { w_w_f,  w_w,  Hsz * Isz };
    tab.d[10] = { w_m_f,  w_m,  Hsz * Isz };
    tab.d[11] = { w_t_f,  w_t,  Hsz * Hsz };
    tab.d[12] = { w_e_f,  w_e,  Hsz * Wsz };
    convert_many<<<dim3(256, 13), 256, 0, stream>>>(tab);
    hipMemsetAsync(zerobuf, 0, 256, stream);

    // e = sigmoid(xw @ w_e^T + b_e)  [98304 x 512], layout [b*T+t]
    ekernel<<<dim3(Msz / 64, Hsz / 64), 256, 0, stream>>>(xw_bf, w_e, b_e, e_bf);

    // pre-pass: all input-only projections, frag-permuted output
    prepass_kernel<<<dim3(Msz / 128, 16), 256, 0, stream>>>(
        x_bf, e_bf, w_d, w_w, w_m, w_rx, w_re, w_zx, w_ze, w_hx,
        b_r, b_z, b_h, zerobuf, prep);

    // persistent recurrence: 256 blocks x 16 waves, K=64 staged chunks
    rnn_kernel<<<Bsz / 16, 1024, 0, stream>>>(prep, w_t, w_rh, w_zh, w_hh, out);
}

// Round 17
// 1550.232 us; speedup vs baseline: 2.2144x; 1.0304x over previous
//
#include <hip/hip_runtime.h>
#include <stdint.h>

#define Bsz 4096
#define Tsz 24
#define Isz 128
#define Hsz 512
#define Wsz 32
#define Msz (Bsz * Tsz)   // 98304 flat rows (b*T+t)

typedef __attribute__((ext_vector_type(8))) short short8;
typedef __attribute__((ext_vector_type(4))) float f32x4;
typedef unsigned short u16;

__device__ __forceinline__ float bf2f(u16 u) {
    union { unsigned int i; float f; } v; v.i = ((unsigned int)u) << 16; return v.f;
}
__device__ __forceinline__ u16 f2bf(float f) {
    union { float f; unsigned int i; } v; v.f = f;
    unsigned int r = v.i + 0x7fffu + ((v.i >> 16) & 1u);
    return (u16)(r >> 16);
}
__device__ __forceinline__ float sigm(float x) { return 1.0f / (1.0f + expf(-x)); }

__device__ __forceinline__ f32x4 MF(short8 a, short8 b, f32x4 c) {
    return __builtin_amdgcn_mfma_f32_16x16x32_bf16(a, b, c, 0, 0, 0);
}
__device__ __forceinline__ short8 ntload8(const u16* p) {
    return __builtin_nontemporal_load((const short8*)p);
}

#define GLOAD_LDS16(SRC, DST) \
    __builtin_amdgcn_global_load_lds( \
        (__attribute__((address_space(1))) void*)(SRC), \
        (__attribute__((address_space(3))) void*)(DST), 16, 0, 0)

// ---------------- f32 -> bf16 conversion ----------------------------------
__global__ __launch_bounds__(256) void convert_big(
    const float* __restrict__ src, u16* __restrict__ dst, int n)
{
    int i = (blockIdx.x * 256 + threadIdx.x) * 4;
    if (i + 4 <= n) {
        float4 v = *(const float4*)(src + i);
        dst[i + 0] = f2bf(v.x); dst[i + 1] = f2bf(v.y);
        dst[i + 2] = f2bf(v.z); dst[i + 3] = f2bf(v.w);
    }
}

struct ConvDesc { const float* src; u16* dst; int n; };
struct ConvTab { ConvDesc d[13]; };

__global__ __launch_bounds__(256) void convert_many(ConvTab tab)
{
    ConvDesc cd = tab.d[blockIdx.y];
    for (int i = (blockIdx.x * 256 + threadIdx.x) * 4; i < cd.n;
         i += gridDim.x * 256 * 4) {
        float4 v = *(const float4*)(cd.src + i);
        cd.dst[i + 0] = f2bf(v.x); cd.dst[i + 1] = f2bf(v.y);
        cd.dst[i + 2] = f2bf(v.z); cd.dst[i + 3] = f2bf(v.w);
    }
}

// ======================= prepass GEMM machinery (r15-exact) =================
struct Seg { const u16* A; int astr; int shift; const u16* W; int wstr; int nkb; };

__device__ __forceinline__ void stage_half(
    u16* ldsT, const u16* gbase, int rstr, int rvf,
    const u16* zerobuf, int wid, int lane)
{
#pragma unroll
    for (int q = 0; q < 4; ++q) {
        int c   = wid * 4 + q;
        int lin = c * 64 + lane;
        int row = lin >> 3;
        int gc  = lin & 7;
        const u16* src = (row >= rvf)
            ? (gbase + (long)row * rstr + ((gc ^ (row & 7)) << 3))
            : zerobuf;
        GLOAD_LDS16(src, ldsT + c * 512);
    }
}

__device__ __forceinline__ void stage_step(
    const Seg* segs, int nseg, int kb, u16* ldsA, u16* ldsB,
    int m0, int n0, const u16* zerobuf, int wid, int lane)
{
    Seg s = segs[0];
    int kloc = kb;
    if (nseg > 1 && kloc >= s.nkb) {
        kloc -= s.nkb; s = segs[1];
        if (nseg > 2 && kloc >= s.nkb) { kloc -= s.nkb; s = segs[2]; }
    }
    int base_row = m0 + s.shift;
    int rvf = base_row < 0 ? -base_row : 0;
    stage_half(ldsA, s.A + (long)base_row * s.astr + kloc * 64, s.astr, rvf,
               zerobuf, wid, lane);
    stage_half(ldsB, s.W + (long)n0 * s.wstr + kloc * 64, s.wstr, 0,
               zerobuf, wid, lane);
}

__device__ __forceinline__ void compute_tile(
    f32x4 acc[4][4], const u16* Ab, const u16* Bb, int wr, int wc, int lane)
{
    const int l15 = lane & 15;
    const int hi = lane >> 4;
#pragma unroll
    for (int ks = 0; ks < 2; ++ks) {
        int kg = ks * 4 + hi;
        short8 a[4], b[4];
#pragma unroll
        for (int am = 0; am < 4; ++am) {
            int row = wr * 64 + am * 16 + l15;
            a[am] = *(const short8*)(Ab + row * 64 + ((kg ^ (row & 7)) << 3));
        }
#pragma unroll
        for (int bn = 0; bn < 4; ++bn) {
            int row = wc * 64 + bn * 16 + l15;
            b[bn] = *(const short8*)(Bb + row * 64 + ((kg ^ (row & 7)) << 3));
        }
#pragma unroll
        for (int am = 0; am < 4; ++am)
#pragma unroll
            for (int bn = 0; bn < 4; ++bn)
                acc[am][bn] = MF(a[am], b[bn], acc[am][bn]);
    }
}

#define GEMM_CORE(SEGS, NSEG, M0, N0W)                                          \
    __shared__ u16 lds[2][2][128 * 64];                                         \
    const int lane = threadIdx.x & 63;                                          \
    const int wid  = threadIdx.x >> 6;                                          \
    const int wr = wid >> 1, wc = wid & 1;                                      \
    f32x4 acc[4][4];                                                            \
    _Pragma("unroll") for (int i_ = 0; i_ < 4; ++i_)                            \
    _Pragma("unroll") for (int j_ = 0; j_ < 4; ++j_)                            \
        acc[i_][j_] = f32x4{0, 0, 0, 0};                                        \
    int nkb = 0;                                                                \
    for (int s_ = 0; s_ < (NSEG); ++s_) nkb += (SEGS)[s_].nkb;                  \
    stage_step((SEGS), (NSEG), 0, lds[0][0], lds[0][1], (M0), (N0W),            \
               zerobuf, wid, lane);                                             \
    int cur = 0;                                                                \
    for (int kb = 0; kb < nkb; ++kb) {                                          \
        __syncthreads();                                                        \
        if (kb + 1 < nkb)                                                       \
            stage_step((SEGS), (NSEG), kb + 1, lds[cur ^ 1][0],                 \
                       lds[cur ^ 1][1], (M0), (N0W), zerobuf, wid, lane);       \
        compute_tile(acc, lds[cur][0], lds[cur][1], wr, wc, lane);              \
        cur ^= 1;                                                               \
    }

// ---------------- e = sigmoid(xw @ w_e^T + b_e), e layout [b*T+t][512] -----
__global__ __launch_bounds__(256) void ekernel(
    const u16* __restrict__ xw, const u16* __restrict__ w_e,
    const float* __restrict__ b_e, u16* __restrict__ eout)
{
    const int lane = threadIdx.x & 63;
    const int wid  = threadIdx.x >> 6;
    const int m0 = blockIdx.x * 64 + (wid >> 1) * 32;
    const int n0 = blockIdx.y * 64 + (wid & 1) * 32;
    f32x4 acc[2][2];
    acc[0][0] = f32x4{0,0,0,0}; acc[0][1] = f32x4{0,0,0,0};
    acc[1][0] = f32x4{0,0,0,0}; acc[1][1] = f32x4{0,0,0,0};
    const int l15 = lane & 15;
    const int klane = (lane >> 4) * 8;
    short8 b0 = *(const short8*)(w_e + (n0 + l15) * Wsz + klane);
    short8 b1 = *(const short8*)(w_e + (n0 + 16 + l15) * Wsz + klane);
#pragma unroll
    for (int am = 0; am < 2; ++am) {
        short8 a = *(const short8*)(xw + (long)(m0 + am * 16 + l15) * Wsz + klane);
        acc[am][0] = MF(a, b0, acc[am][0]);
        acc[am][1] = MF(a, b1, acc[am][1]);
    }
    const int col = lane & 15;
    const int r0 = (lane >> 4) * 4;
#pragma unroll
    for (int am = 0; am < 2; ++am)
#pragma unroll
        for (int bn = 0; bn < 2; ++bn)
#pragma unroll
            for (int i = 0; i < 4; ++i) {
                long row = m0 + am * 16 + r0 + i;
                int g = n0 + bn * 16 + col;
                eout[row * Hsz + g] = f2bf(sigm(acc[am][bn][i] + b_e[g]));
            }
}

// ---------------- pre-pass (r15 body; XCD-stream block swizzle) -------------
// 1-D grid 12288. Physical block p -> XCD p%8 (round-robin heuristic).
// q = p>>3 is the position within that XCD's stream; the 16 (group,n)-tiles
// of one m-panel occupy 16 consecutive q slots -> co-resident on one XCD,
// so the shared A-panel (x rows / e rows) is fetched from HBM once and
// re-read from that XCD's L2. Mapping is bijective; correctness does not
// depend on the dispatch heuristic.
__global__ __launch_bounds__(256, 2) void prepass_kernel(
    const u16* __restrict__ x, const u16* __restrict__ e,
    const u16* __restrict__ w_d, const u16* __restrict__ w_w,
    const u16* __restrict__ w_m, const u16* __restrict__ w_rx,
    const u16* __restrict__ w_re, const u16* __restrict__ w_zx,
    const u16* __restrict__ w_ze, const u16* __restrict__ w_hx,
    const float* __restrict__ b_r, const float* __restrict__ b_z,
    const float* __restrict__ b_h,
    const u16* __restrict__ zerobuf, u16* __restrict__ prep)
{
    const int p = blockIdx.x;
    const int xcd = p & 7, q = p >> 3;
    const int mblk = xcd + 8 * (q >> 4);   // 0..767
    const int yy = q & 15;
    const int m0 = mblk * 128;
    const int group = yy >> 2;
    const int nin = (yy & 3) * 128;
    Seg segs[3];
    int nseg;
    const float* bias = nullptr;
    if (group == 0) {
        segs[0] = { x, Isz, -1 * Tsz,  w_d, Isz, Isz / 64 };
        segs[1] = { x, Isz, -7 * Tsz,  w_w, Isz, Isz / 64 };
        segs[2] = { x, Isz, -30 * Tsz, w_m, Isz, Isz / 64 };
        nseg = 3;
    } else if (group == 1) {
        segs[0] = { x, Isz, 0, w_rx, Isz, Isz / 64 };
        segs[1] = { e, Hsz, 0, w_re, Hsz, Hsz / 64 };
        nseg = 2; bias = b_r;
    } else if (group == 2) {
        segs[0] = { x, Isz, 0, w_zx, Isz, Isz / 64 };
        segs[1] = { e, Hsz, 0, w_ze, Hsz, Hsz / 64 };
        nseg = 2; bias = b_z;
    } else {
        segs[0] = { x, Isz, 0, w_hx, Isz, Isz / 64 };
        nseg = 1; bias = b_h;
    }
    GEMM_CORE(segs, nseg, m0, nin)
    const int l15 = lane & 15, hi4v = (lane >> 4) * 4;
#pragma unroll
    for (int am = 0; am < 4; ++am)
#pragma unroll
        for (int bn = 0; bn < 4; ++bn) {
            int colH = nin + wc * 64 + bn * 16 + l15;
            float bv = bias ? bias[colH] : 0.0f;
            int wv = colH >> 5, ntv = (colH >> 4) & 1, l15v = colH & 15;
#pragma unroll
            for (int i = 0; i < 4; ++i) {
                long m = m0 + wr * 64 + am * 16 + hi4v + i;
                int b = (int)(m / Tsz), t = (int)(m % Tsz);
                int bblk = b >> 4, rowin = b & 15;
                int hiv = rowin >> 2, iv = rowin & 3;
                long idx = (((long)(bblk * Tsz + t) * 4 + group) * 16 + wv) * 512
                           + (hiv * 16 + l15v) * 8 + ntv * 4 + iv;
                prep[idx] = f2bf(acc[am][bn][i] + bv);
            }
        }
}

// ======================= persistent recurrence (r15-exact) ==================
#define SROW 528

__device__ __forceinline__ int swz(int row, int col) {
    return row * SROW + ((((col >> 3) ^ (row & 7)) << 3) | (col & 7));
}

__device__ __forceinline__ void stage_chunk64(
    const u16* __restrict__ Wm, int c, u16* buf, int wave, int lane)
{
    int s1 = wave * 128 + lane;
    int s2 = s1 + 64;
    int p1 = s1 >> 3, g1 = (s1 & 7) ^ (p1 & 7);
    int p2 = s2 >> 3, g2 = (s2 & 7) ^ (p2 & 7);
#pragma unroll
    for (int h = 0; h < 2; ++h) {
        GLOAD_LDS16(Wm + (long)(2 * p1 + (g1 >> 2)) * 512
                       + c * 64 + h * 32 + (g1 & 3) * 8,
                    buf + h * 16384 + wave * 1024);
        GLOAD_LDS16(Wm + (long)(2 * p2 + (g2 >> 2)) * 512
                       + c * 64 + h * 32 + (g2 & 3) * 8,
                    buf + h * 16384 + wave * 1024 + 512);
    }
}

__device__ __forceinline__ void wpass_staged(
    f32x4 acc[2], const u16* aS, const u16* __restrict__ Wm,
    u16* wbuf0, u16* wbuf1, int bo0, int rx, int l15, int hi,
    int wave, int lane)
{
    const u16* ap = aS + l15 * SROW;
    stage_chunk64(Wm, 0, wbuf0, wave, lane);
#pragma unroll 1
    for (int c = 0; c < 8; ++c) {
        __syncthreads();
        u16* cur = (c & 1) ? wbuf1 : wbuf0;
        u16* nxt = (c & 1) ? wbuf0 : wbuf1;
        if (c < 7) stage_chunk64(Wm, c + 1, nxt, wave, lane);
#pragma unroll
        for (int kk = 0; kk < 2; ++kk) {
            short8 b0 = *(const short8*)(cur + kk * 16384 + bo0);
            short8 b1 = *(const short8*)(cur + kk * 16384 + bo0 + 512);
            short8 a = *(const short8*)(
                ap + ((((c * 2 + kk) * 4 + hi) ^ rx) << 3));
            acc[0] = MF(a, b0, acc[0]);
            acc[1] = MF(a, b1, acc[1]);
        }
    }
}

#define FOR_FRAG \
    _Pragma("unroll") for (int nt2 = 0; nt2 < 2; ++nt2) \
    _Pragma("unroll") for (int i = 0; i < 4; ++i)

__global__ __launch_bounds__(1024, 4) void rnn_kernel(
    const u16* __restrict__ prep, const u16* __restrict__ w_t_,
    const u16* __restrict__ w_rh, const u16* __restrict__ w_zh,
    const u16* __restrict__ w_hh, float* __restrict__ out)
{
    __shared__ __align__(16) u16 hS[16 * SROW];        // h / ho / rh
    __shared__ __align__(16) u16 wbuf0[32 * 1024];     // 64KB chunk buf A
    __shared__ __align__(16) u16 wbuf1[32 * 1024];     // 64KB chunk buf B
    const int tid = threadIdx.x;
    const int lane = tid & 63;
    const int wave = tid >> 6;
    const int l15 = lane & 15, hi = lane >> 4;
    const int rx = l15 & 7;
    const int n0 = wave * 32;
    const long b0 = (long)blockIdx.x * 16;
    const int bo0 = (wave * 128 + (l15 >> 1) * 8
                     + ((hi + 4 * (l15 & 1)) ^ (l15 >> 1))) * 8;

    for (int i = tid * 8; i < 16 * SROW; i += 1024 * 8)
        *(short8*)(hS + i) = (short8)0;
    __syncthreads();

    const u16* pbase = prep + (long)blockIdx.x * (Tsz * 4 * 8192)
                       + wave * 512 + lane * 8;

#pragma unroll 1
    for (int t = 0; t < Tsz; ++t) {
        const u16* pt = pbase + (long)t * 4 * 8192;
        short8 po = ntload8(pt);

        // ---- stage A: ho = sigm(pre_o + h @ w_t^T)  [reads hS = h] ----
        f32x4 accO[2];
        accO[0] = f32x4{0,0,0,0}; accO[1] = f32x4{0,0,0,0};
        wpass_staged(accO, hS, w_t_, wbuf0, wbuf1, bo0, rx, l15, hi,
                     wave, lane);
        float hov[2][4];
        FOR_FRAG {
            float v = sigm(accO[nt2][i] + bf2f((u16)po[nt2 * 4 + i]));
            hov[nt2][i] = v;
        }
        __syncthreads();   // all waves done reading hS(=h)
        FOR_FRAG hS[swz(hi * 4 + i, n0 + nt2 * 16 + l15)] = f2bf(hov[nt2][i]);

        // ---- stage B: r,z = sigm(pre + ho @ w^T)  [reads hS = ho] ----
        short8 pr = ntload8(pt + 8192);
        short8 pz = ntload8(pt + 2 * 8192);
        f32x4 accR[2];
        accR[0] = f32x4{0,0,0,0}; accR[1] = f32x4{0,0,0,0};
        wpass_staged(accR, hS, w_rh, wbuf0, wbuf1, bo0, rx, l15, hi,
                     wave, lane);
        f32x4 accZ[2];
        accZ[0] = f32x4{0,0,0,0}; accZ[1] = f32x4{0,0,0,0};
        wpass_staged(accZ, hS, w_zh, wbuf0, wbuf1, bo0, rx, l15, hi,
                     wave, lane);
        float zv[2][4], rhv[2][4];
        FOR_FRAG {
            zv[nt2][i] = sigm(accZ[nt2][i] + bf2f((u16)pz[nt2 * 4 + i]));
            float rv = sigm(accR[nt2][i] + bf2f((u16)pr[nt2 * 4 + i]));
            rhv[nt2][i] = rv * hov[nt2][i];
        }
        __syncthreads();   // all waves done reading hS(=ho)
        FOR_FRAG hS[swz(hi * 4 + i, n0 + nt2 * 16 + l15)] = f2bf(rhv[nt2][i]);

        // ---- stage C: h~ = tanh(pre_h + rh @ w_hh^T)  [reads hS = rh] ----
        short8 ph = ntload8(pt + 3 * 8192);
        f32x4 accH[2];
        accH[0] = f32x4{0,0,0,0}; accH[1] = f32x4{0,0,0,0};
        wpass_staged(accH, hS, w_hh, wbuf0, wbuf1, bo0, rx, l15, hi,
                     wave, lane);
        __syncthreads();   // all waves done reading hS(=rh)
        FOR_FRAG {
            int row = hi * 4 + i, col = n0 + nt2 * 16 + l15;
            float htl = tanhf(accH[nt2][i] + bf2f((u16)ph[nt2 * 4 + i]));
            float z = zv[nt2][i];
            float hn = (1.0f - z) * hov[nt2][i] + z * htl;
            __builtin_nontemporal_store(
                hn, &out[((b0 + row) * Tsz + t) * (long)Hsz + col]);
            hS[swz(row, col)] = f2bf(hn);
        }
    }
}

extern "C" void kernel_launch(void* const* d_in, const int* in_sizes, int n_in,
                              void* d_out, int out_size, void* d_ws, size_t ws_size,
                              hipStream_t stream) {
    const float* x_f    = (const float*)d_in[0];
    const float* xw_f   = (const float*)d_in[1];
    const float* w_rx_f = (const float*)d_in[2];
    const float* w_rh_f = (const float*)d_in[3];
    const float* w_re_f = (const float*)d_in[4];
    const float* b_r    = (const float*)d_in[5];
    const float* w_zx_f = (const float*)d_in[6];
    const float* w_zh_f = (const float*)d_in[7];
    const float* w_ze_f = (const float*)d_in[8];
    const float* b_z    = (const float*)d_in[9];
    const float* w_hx_f = (const float*)d_in[10];
    const float* w_hh_f = (const float*)d_in[11];
    const float* b_h    = (const float*)d_in[12];
    const float* w_d_f  = (const float*)d_in[13];
    const float* w_w_f  = (const float*)d_in[14];
    const float* w_m_f  = (const float*)d_in[15];
    const float* w_t_f  = (const float*)d_in[16];
    const float* w_e_f  = (const float*)d_in[17];
    const float* b_e    = (const float*)d_in[18];
    float* out = (float*)d_out;

    char* ws = (char*)d_ws;
    size_t off = 0;
    auto alloc = [&](size_t bytes) {
        size_t o = off; off = (off + bytes + 255) & ~(size_t)255; return o;
    };
    const size_t nx  = (size_t)Msz * Isz;
    const size_t nxw = (size_t)Msz * Wsz;

    u16* x_bf  = (u16*)(ws + alloc(nx * 2));
    u16* xw_bf = (u16*)(ws + alloc(nxw * 2));
    u16* w_rx  = (u16*)(ws + alloc(Hsz * Isz * 2));
    u16* w_rh  = (u16*)(ws + alloc(Hsz * Hsz * 2));
    u16* w_re  = (u16*)(ws + alloc(Hsz * Hsz * 2));
    u16* w_zx  = (u16*)(ws + alloc(Hsz * Isz * 2));
    u16* w_zh  = (u16*)(ws + alloc(Hsz * Hsz * 2));
    u16* w_ze  = (u16*)(ws + alloc(Hsz * Hsz * 2));
    u16* w_hx  = (u16*)(ws + alloc(Hsz * Isz * 2));
    u16* w_hh  = (u16*)(ws + alloc(Hsz * Hsz * 2));
    u16* w_d   = (u16*)(ws + alloc(Hsz * Isz * 2));
    u16* w_w   = (u16*)(ws + alloc(Hsz * Isz * 2));
    u16* w_m   = (u16*)(ws + alloc(Hsz * Isz * 2));
    u16* w_t   = (u16*)(ws + alloc(Hsz * Hsz * 2));
    u16* w_e   = (u16*)(ws + alloc(Hsz * Wsz * 2));
    u16* e_bf  = (u16*)(ws + alloc((size_t)Msz * Hsz * 2));   // 96 MB [b*T+t]
    u16* prep  = (u16*)(ws + alloc((size_t)Msz * 2048 * 2));  // 384 MB permuted
    u16* zerobuf = (u16*)(ws + alloc(256));

    convert_big<<<(int)(nx / 1024), 256, 0, stream>>>(x_f, x_bf, (int)nx);
    convert_big<<<(int)(nxw / 1024), 256, 0, stream>>>(xw_f, xw_bf, (int)nxw);
    ConvTab tab;
    tab.d[0]  = { w_rx_f, w_rx, Hsz * Isz };
    tab.d[1]  = { w_rh_f, w_rh, Hsz * Hsz };
    tab.d[2]  = { w_re_f, w_re, Hsz * Hsz };
    tab.d[3]  = { w_zx_f, w_zx, Hsz * Isz };
    tab.d[4]  = { w_zh_f, w_zh, Hsz * Hsz };
    tab.d[5]  = { w_ze_f, w_ze, Hsz * Hsz };
    tab.d[6]  = { w_hx_f, w_hx, Hsz * Isz };
    tab.d[7]  = { w_hh_f, w_hh, Hsz * Hsz };
    tab.d[8]  = { w_d_f,  w_d,  Hsz * Isz };
    tab.d[9]  = { w_w_f,  w_w,  Hsz * Isz };
    tab.d[10] = { w_m_f,  w_m,  Hsz * Isz };
    tab.d[11] = { w_t_f,  w_t,  Hsz * Hsz };
    tab.d[12] = { w_e_f,  w_e,  Hsz * Wsz };
    convert_many<<<dim3(256, 13), 256, 0, stream>>>(tab);
    hipMemsetAsync(zerobuf, 0, 256, stream);

    // e = sigmoid(xw @ w_e^T + b_e)  [98304 x 512], layout [b*T+t]
    ekernel<<<dim3(Msz / 64, Hsz / 64), 256, 0, stream>>>(xw_bf, w_e, b_e, e_bf);

    // pre-pass: 1-D grid, XCD-stream swizzle (16 tiles of one m-panel are
    // consecutive on one XCD -> shared A-panel is L2-resident)
    prepass_kernel<<<Msz / 128 * 16, 256, 0, stream>>>(
        x_bf, e_bf, w_d, w_w, w_m, w_rx, w_re, w_zx, w_ze, w_hx,
        b_r, b_z, b_h, zerobuf, prep);

    // persistent recurrence: 256 blocks x 16 waves, K=64 staged chunks
    rnn_kernel<<<Bsz / 16, 1024, 0, stream>>>(prep, w_t, w_rh, w_zh, w_hh, out);
}